// Round 2
// baseline (2097.954 us; speedup 1.0000x reference)
//
#include <hip/hip_runtime.h>
#include <math.h>

#define Bb 16
#define Nn 2048
#define Dd 256
#define Cc 128
#define Kk 20
#define BIG_NEG -1.0e9f

// workspace layout (float offsets)
#define WS_EMIS   0
#define WS_MSC    (WS_EMIS + Bb*Nn*Cc)          // means * inv_var, bf16  [C][D]
#define WS_XQ     (WS_MSC + Cc*Dd)              // sum f^2*inv_var  [B*N]
#define WS_ECHAN  (WS_XQ + Bb*Nn)               // const - 0.5*mq   [C]
#define WS_T      (WS_ECHAN + Cc)               // exp(trans_lp)    [C][C]
#define WS_LEN    (WS_T + Cc*Cc)                // len_lp           [K][C]
#define WS_INIT   (WS_LEN + Kk*Cc)              // init_lp          [C]
#define WS_IVAR   (WS_INIT + Cc)                // 1/cov            [D]

typedef __attribute__((ext_vector_type(8))) short short8;
typedef __attribute__((ext_vector_type(4))) float float4v;

__device__ __forceinline__ unsigned short f32_to_bf16(float x) {
  unsigned int u = __builtin_bit_cast(unsigned int, x);
  u = (u + 0x7FFFu + ((u >> 16) & 1u)) >> 16;
  return (unsigned short)u;
}

#define DPP_STEP(x, op, ctrl, rmask)                                          \
  do {                                                                        \
    int _yi = __builtin_amdgcn_update_dpp(                                    \
        __builtin_bit_cast(int, x), __builtin_bit_cast(int, x), ctrl, rmask,  \
        0xF, true);                                                           \
    x = op(x, __builtin_bit_cast(float, _yi));                                \
  } while (0)

__device__ __forceinline__ float dpp_add(float a, float b) { return a + b; }

__device__ __forceinline__ float wave_max64(float x) {
  DPP_STEP(x, fmaxf, 0xB1, 0xF);
  DPP_STEP(x, fmaxf, 0x4E, 0xF);
  DPP_STEP(x, fmaxf, 0x141, 0xF);
  DPP_STEP(x, fmaxf, 0x140, 0xF);
  DPP_STEP(x, fmaxf, 0x142, 0xA);
  DPP_STEP(x, fmaxf, 0x143, 0xC);
  return __builtin_bit_cast(float,
      __builtin_amdgcn_readlane(__builtin_bit_cast(int, x), 63));
}

__device__ __forceinline__ float wave_sum64(float x) {
  DPP_STEP(x, dpp_add, 0xB1, 0xF);
  DPP_STEP(x, dpp_add, 0x4E, 0xF);
  DPP_STEP(x, dpp_add, 0x141, 0xF);
  DPP_STEP(x, dpp_add, 0x140, 0xF);
  DPP_STEP(x, dpp_add, 0x142, 0xA);
  DPP_STEP(x, dpp_add, 0x143, 0xC);
  return __builtin_bit_cast(float,
      __builtin_amdgcn_readlane(__builtin_bit_cast(int, x), 63));
}

// ---------------- small precompute (1 block, 256 threads) ----------------
__global__ void prep_kernel(const float* __restrict__ means,
                            const float* __restrict__ cov,
                            const float* __restrict__ tl,
                            const float* __restrict__ il,
                            const float* __restrict__ plr,
                            float* __restrict__ ws) {
  __shared__ float s_iv[Dd];
  __shared__ float s_red[4];
  __shared__ float s_tlse[Cc];
  int tid = threadIdx.x;

  float cv = cov[tid];
  float iv = 1.0f / cv;
  s_iv[tid] = iv;
  ws[WS_IVAR + tid] = iv;
  float lg = __logf(cv);
  #pragma unroll
  for (int off = 1; off < 64; off <<= 1) lg += __shfl_xor(lg, off, 64);
  if ((tid & 63) == 0) s_red[tid >> 6] = lg;
  __syncthreads();
  float logdet = s_red[0] + s_red[1] + s_red[2] + s_red[3];
  float cconst = -0.5f * ((float)Dd * 1.8378770664093453f + logdet);

  // msc in bf16 (B-frag operand for emission MFMA)
  unsigned short* mscb = (unsigned short*)(ws + WS_MSC);
  for (int idx = tid; idx < Cc * Dd; idx += 256) {
    int d = idx & (Dd - 1);
    mscb[idx] = f32_to_bf16(means[idx] * s_iv[d]);
  }
  if (tid < Cc) {
    float acc = 0.0f;
    for (int d = 0; d < Dd; d++) {
      float m = means[tid * Dd + d];
      acc = fmaf(m * m, s_iv[d], acc);
    }
    ws[WS_ECHAN + tid] = cconst - 0.5f * acc;
  }
  for (int idx = tid; idx < Kk * Cc; idx += 256) {
    int L = idx / Cc + 1;
    int c = idx & (Cc - 1);
    float r = plr[c];
    ws[WS_LEN + idx] = (float)L * r - __expf(r) - lgammaf((float)(L + 1));
  }

  __syncthreads();
  float x = (tid < Cc) ? il[tid] : -INFINITY;
  float mx = x;
  #pragma unroll
  for (int off = 1; off < 64; off <<= 1) mx = fmaxf(mx, __shfl_xor(mx, off, 64));
  if ((tid & 63) == 0) s_red[tid >> 6] = mx;
  __syncthreads();
  float M = fmaxf(s_red[0], s_red[1]);
  float se = (tid < Cc) ? __expf(x - M) : 0.0f;
  #pragma unroll
  for (int off = 1; off < 64; off <<= 1) se += __shfl_xor(se, off, 64);
  __syncthreads();
  if ((tid & 63) == 0) s_red[tid >> 6] = se;
  __syncthreads();
  float lse = M + __logf(s_red[0] + s_red[1]);
  if (tid < Cc) ws[WS_INIT + tid] = x - lse;

  if (tid < Cc) {
    int j = tid;
    float m2 = -INFINITY;
    for (int i = 0; i < Cc; i++) if (i != j) m2 = fmaxf(m2, tl[i * Cc + j]);
    float s2 = 0.0f;
    for (int i = 0; i < Cc; i++) if (i != j) s2 += __expf(tl[i * Cc + j] - m2);
    s_tlse[j] = m2 + __logf(s2);
  }
  __syncthreads();
  for (int idx = tid; idx < Cc * Cc; idx += 256) {
    int i = idx / Cc;
    int j = idx & (Cc - 1);
    ws[WS_T + idx] = (i == j) ? 0.0f : __expf(tl[idx] - s_tlse[j]);
  }
}

// ---------------- xq[b,n] = sum_d f^2 * inv_var (one wave per position) ----------------
__global__ void xq_kernel(const float* __restrict__ f, float* __restrict__ ws) {
  int pos = blockIdx.x * 4 + (threadIdx.x >> 6);
  int lane = threadIdx.x & 63;
  const float4 fv = *(const float4*)&f[(size_t)pos * Dd + lane * 4];
  const float4 vv = *(const float4*)&ws[WS_IVAR + lane * 4];
  float a = fv.x * fv.x * vv.x + fv.y * fv.y * vv.y +
            fv.z * fv.z * vv.z + fv.w * fv.w * vv.w;
  #pragma unroll
  for (int off = 1; off < 64; off <<= 1) a += __shfl_xor(a, off, 64);
  if (lane == 0) ws[WS_XQ + pos] = a;
}

// ---------------- emission via MFMA: 32n x 128c per block, 4 waves ----------------
__launch_bounds__(256)
__global__ void emis_mfma_kernel(const float* __restrict__ f, float* __restrict__ ws) {
  const unsigned short* msc = (const unsigned short*)(ws + WS_MSC);
  float* emis = ws + WS_EMIS;
  int tid = threadIdx.x;
  int w = tid >> 6, lane = tid & 63, g = lane >> 4, l16 = lane & 15;
  int b = blockIdx.x >> 6;
  int n0 = (blockIdx.x & 63) << 5;
  int c0 = w << 5;

  const float* fbase = f + (size_t)(b * Nn + n0) * Dd;
  float4v acc[2][2];
  #pragma unroll
  for (int rt = 0; rt < 2; rt++)
    #pragma unroll
    for (int ct = 0; ct < 2; ct++) acc[rt][ct] = (float4v){0.f, 0.f, 0.f, 0.f};

  #pragma unroll
  for (int k0 = 0; k0 < Dd; k0 += 32) {
    int kk = k0 + g * 8;
    short8 afr[2], bfr[2];
    #pragma unroll
    for (int rt = 0; rt < 2; rt++) {
      const float* src = fbase + (size_t)(rt * 16 + l16) * Dd + kk;
      float4 v0 = *(const float4*)src;
      float4 v1 = *(const float4*)(src + 4);
      short8 fr;
      fr[0] = (short)f32_to_bf16(v0.x); fr[1] = (short)f32_to_bf16(v0.y);
      fr[2] = (short)f32_to_bf16(v0.z); fr[3] = (short)f32_to_bf16(v0.w);
      fr[4] = (short)f32_to_bf16(v1.x); fr[5] = (short)f32_to_bf16(v1.y);
      fr[6] = (short)f32_to_bf16(v1.z); fr[7] = (short)f32_to_bf16(v1.w);
      afr[rt] = fr;
    }
    #pragma unroll
    for (int ct = 0; ct < 2; ct++)
      bfr[ct] = *(const short8*)&msc[(size_t)(c0 + ct * 16 + l16) * Dd + kk];
    #pragma unroll
    for (int rt = 0; rt < 2; rt++)
      #pragma unroll
      for (int ct = 0; ct < 2; ct++)
        acc[rt][ct] = __builtin_amdgcn_mfma_f32_16x16x32_bf16(afr[rt], bfr[ct], acc[rt][ct], 0, 0, 0);
  }

  #pragma unroll
  for (int rt = 0; rt < 2; rt++) {
    #pragma unroll
    for (int ct = 0; ct < 2; ct++) {
      int cc = c0 + ct * 16 + l16;
      float ec = ws[WS_ECHAN + cc];
      #pragma unroll
      for (int r = 0; r < 4; r++) {
        int row = rt * 16 + g * 4 + r;
        int nn = n0 + row;
        emis[(size_t)(b * Nn + nn) * Cc + cc] =
            ec - 0.5f * ws[WS_XQ + b * Nn + nn] + acc[rt][ct][r];
      }
    }
  }
}

// ---------------- semi-Markov scan, multiplicative state, FRESH per-step norm ----------------
// 4 batches per block (512 threads = 8 waves -> 2 waves/SIMD for TLP).
// State: E[k] = exp(beta_{t-k} - cum_{t-k} - R_t), R_t = A_t - cum[t]; q = exp(beta_{t-1}-A_{t-1}).
// Pre-barrier (short chain, no transcendentals): S = fma(q,elen0,Stail); v = S*ee;
// wv = wave_max(v) [FRESH -> deadbeat scale tracking, A_t = M_t exactly; the deferred-r
// variant had poles on the unit circle and diverged]; p = v*rcp(wv) <= 1.
// Post-barrier: la_w = me_w + log wv_w; dla = max; sA/sB = exp(la-dla); sch = s_own*rcp(wv_own)*ee;
// E-shift multiplicative; q_next = (p x T^T) combined with sA/sB = exp(beta_t - A_t) exactly.
// Output anchored on exact-order cum: a = cum[t] + Dlt + log S, Dlt = Kahan sum of (dla - e).
__launch_bounds__(512)
__global__ void scan_kernel(const int* __restrict__ lengths,
                            const float* __restrict__ ws,
                            float* __restrict__ out) {
  __shared__ __align__(16) unsigned short lds_pb[4][2][Cc];  // p bf16, ping-pong
  __shared__ __align__(16) float lds_sc[4][2][4];  // batch, buf : {wvA, meA, wvB, meB}
  __shared__ float lds_out[4][2][2];               // batch, wave : {M*, ps}

  int tid = threadIdx.x;
  int w8 = tid >> 6;
  int bi = w8 >> 1;          // batch within block (0..3)
  int w = w8 & 1;            // wave within batch
  int lane = tid & 63;
  int g = lane >> 4;
  int c = (w << 6) | lane;   // channel 0..127
  int b = (blockIdx.x << 2) | bi;
  int len_b = lengths[b];
  const float* emis = ws + WS_EMIS + (size_t)b * Nn * Cc;

  // T fragments (MFMA B operand): lane holds T[w*64+nt*16+(lane&15)][kt*32+g*8+j]
  short8 Tf[4][4];
  {
    const float* T = ws + WS_T;
    int row_lo = w * 64 + (lane & 15);
    int kg = g * 8;
    #pragma unroll
    for (int nt = 0; nt < 4; nt++)
      #pragma unroll
      for (int kt = 0; kt < 4; kt++) {
        const float* src = &T[(size_t)(row_lo + nt * 16) * Cc + kt * 32 + kg];
        short8 fr;
        #pragma unroll
        for (int j = 0; j < 8; j++) fr[j] = (short)f32_to_bf16(src[j]);
        Tf[nt][kt] = fr;
      }
  }

  // elen[d] = exp(length lp for duration d+1)
  float elen[Kk];
  #pragma unroll
  for (int k2 = 0; k2 < Kk; k2++) elen[k2] = __expf(ws[WS_LEN + k2 * Cc + c]);
  float elen0 = elen[0];

  // E[j] holds duration slot k = j+2 (slot k=1 carried by q)
  float E[Kk - 1];
  #pragma unroll
  for (int k2 = 0; k2 < Kk - 1; k2++) E[k2] = 0.0f;

  float q = __expf(ws[WS_INIT + c]);   // exp(beta_0 - A_0), A_0 = 0
  float Stail = 0.0f;
  float cum = 0.0f;                    // exact same accumulation order as reference cumsum
  float Dlt = 0.0f, dcomp = 0.0f;      // Kahan-compensated Delta = A_{t-1} - cum[t-1]
  float Mb = 0.0f;                     // output max, captured at t == len

  // emission prefetch: e[i] = row (t-1) for step t = tg+i
  float e[8], en[8], me[8];
  #pragma unroll
  for (int j = 0; j < 8; j++) e[j] = emis[(size_t)j * Cc + c];
  #pragma unroll
  for (int j = 0; j < 8; j++) me[j] = wave_max64(e[j]);
  float eecur = __expf(e[0] - me[0]);

  for (int tg = 1; tg <= Nn; tg += 8) {
    #pragma unroll
    for (int i = 0; i < 8; i++) {
      int t = tg + i;
      int buf = t & 1;
      bool active = (t <= len_b);
      bool fin = (t == len_b);
      float ecur = e[i];
      float S = 0.0f, a = 0.0f;

      // ---- pre-barrier: q -> fma -> mul -> wavemax -> rcp -> mul -> bf16 -> ds_write ----
      if (active) {
        S = fmaf(q, elen0, Stail);
        if (fin) {
          // alpha_t(c) = cum[t] + Delta_{t-1} + log S_t  (cum-anchored, exact-order)
          a = (cum + ecur) + Dlt + __logf(S);
          float Mw = wave_max64(a);
          if (lane == 0) lds_out[bi][w][0] = Mw;
        } else {
          float v = S * eecur;                       // exp(alpha_t - A_{t-1} - me_w)
          float wv = fmaxf(wave_max64(v), 1.0e-30f); // FRESH wave max (stability!)
          float p = v * __builtin_amdgcn_rcpf(wv);   // <= 1 by construction
          lds_pb[bi][buf][c] = f32_to_bf16(p);
          if (lane == 0) {
            lds_sc[bi][buf][w * 2] = wv;
            lds_sc[bi][buf][w * 2 + 1] = me[i];
          }
        }
      }
      __syncthreads();   // the ONE barrier per step (all 8 waves)

      // ---- post-barrier ----
      if (active) {
        if (fin) {
          Mb = fmaxf(lds_out[bi][0][0], lds_out[bi][1][0]);
          float ps = wave_sum64(__expf(a - Mb));
          if (lane == 0) lds_out[bi][w][1] = ps;
        } else {
          if (i == 0) {   // group prefetch: rows tg+7 .. tg+14
            #pragma unroll
            for (int j = 0; j < 8; j++) {
              int rr = tg + 7 + j;
              if (rr > Nn - 1) rr = Nn - 1;
              en[j] = emis[(size_t)rr * Cc + c];
            }
          }
          // issue p-fragment LDS reads early
          const unsigned short* pb = lds_pb[bi][buf];
          short8 pa[4];
          #pragma unroll
          for (int kt = 0; kt < 4; kt++)
            pa[kt] = *(const short8*)&pb[kt * 32 + g * 8];
          float4 scv = *(const float4*)&lds_sc[bi][buf][0];  // wvA, meA, wvB, meB

          // scale bookkeeping (off the serial chain)
          float laA = scv.y + __logf(scv.x);
          float laB = scv.w + __logf(scv.z);
          float dla = fmaxf(laA, laB);
          float sA = __expf(laA - dla);
          float sB = __expf(laB - dla);
          float s_own = (w == 0) ? sA : sB;
          float wv_own = (w == 0) ? scv.x : scv.z;
          float sig = s_own * __builtin_amdgcn_rcpf(wv_own); // exp(me_own - dla)
          float sch = sig * eecur;                           // exp(e_t - dla)

          // shift the span window (multiplicative, no exps)
          #pragma unroll
          for (int k2 = Kk - 2; k2 >= 1; k2--) E[k2] = E[k2 - 1] * sch;
          E[0] = q * sch;                 // duration-2 slot <- old duration-1

          // Stail = sum_{k=2..20} E_slot * elen  (4-acc fma tree)
          float s0 = E[0] * elen[1];
          float s1 = E[1] * elen[2];
          float s2 = E[2] * elen[3];
          float s3 = E[3] * elen[4];
          s0 = fmaf(E[4], elen[5], s0);
          s1 = fmaf(E[5], elen[6], s1);
          s2 = fmaf(E[6], elen[7], s2);
          s3 = fmaf(E[7], elen[8], s3);
          s0 = fmaf(E[8], elen[9], s0);
          s1 = fmaf(E[9], elen[10], s1);
          s2 = fmaf(E[10], elen[11], s2);
          s3 = fmaf(E[11], elen[12], s3);
          s0 = fmaf(E[12], elen[13], s0);
          s1 = fmaf(E[13], elen[14], s1);
          s2 = fmaf(E[14], elen[15], s2);
          s3 = fmaf(E[15], elen[16], s3);
          s0 = fmaf(E[16], elen[17], s0);
          s1 = fmaf(E[17], elen[18], s1);
          s2 = fmaf(E[18], elen[19], s2);
          Stail = (s0 + s1) + (s2 + s3);

          // spread next-group wave-maxes across steps (loads long since landed)
          if (i >= 2) me[i - 2] = wave_max64(en[i - 2]);

          // Delta = A - cum (Kahan), cum exact-order
          {
            float dd = dla - ecur;
            float y = dd - dcomp;
            float t2 = Dlt + y;
            dcomp = (t2 - Dlt) - y;
            Dlt = t2;
          }
          cum += ecur;
          if (i < 7) eecur = __expf(e[i + 1] - me[i + 1]);

          // MFMA matvec: q^T = p x T^T, split per-wave scale halves
          float4v z = {0.0f, 0.0f, 0.0f, 0.0f};
          float4v accA[4], accB[4];
          #pragma unroll
          for (int nt = 0; nt < 4; nt++) {
            accA[nt] = __builtin_amdgcn_mfma_f32_16x16x32_bf16(pa[1], Tf[nt][1],
                         __builtin_amdgcn_mfma_f32_16x16x32_bf16(pa[0], Tf[nt][0], z, 0, 0, 0),
                         0, 0, 0);
            accB[nt] = __builtin_amdgcn_mfma_f32_16x16x32_bf16(pa[3], Tf[nt][3],
                         __builtin_amdgcn_mfma_f32_16x16x32_bf16(pa[2], Tf[nt][2], z, 0, 0, 0),
                         0, 0, 0);
          }
          float qa0 = (g == 0) ? accA[0][0] : accA[1][0];
          float qa1 = (g == 2) ? accA[2][0] : accA[3][0];
          float qa = (g < 2) ? qa0 : qa1;
          float qb0 = (g == 0) ? accB[0][0] : accB[1][0];
          float qb1 = (g == 2) ? accB[2][0] : accB[3][0];
          float qb = (g < 2) ? qb0 : qb1;
          q = qa * sA + qb * sB;          // exp(beta_t - A_t), exactly
        }
      }
      // deferred output emission (ordered by the step-(len+1) barrier)
      if (t == len_b + 1 && lane == 0 && w == 0)
        out[b] = Mb + __logf(lds_out[bi][0][1] + lds_out[bi][1][1]);
    }
    // group boundary: finish slots 6,7 and rotate prefetch buffers
    me[6] = wave_max64(en[6]);
    me[7] = wave_max64(en[7]);
    #pragma unroll
    for (int j = 0; j < 8; j++) e[j] = en[j];
    eecur = __expf(e[0] - me[0]);
  }
  __syncthreads();
  if (len_b == Nn && lane == 0 && w == 0)
    out[b] = Mb + __logf(lds_out[bi][0][1] + lds_out[bi][1][1]);
}

extern "C" void kernel_launch(void* const* d_in, const int* in_sizes, int n_in,
                              void* d_out, int out_size, void* d_ws, size_t ws_size,
                              hipStream_t stream) {
  const float* features = (const float*)d_in[0];
  const int* lengths = (const int*)d_in[1];
  const float* means = (const float*)d_in[2];
  const float* cov = (const float*)d_in[3];
  const float* tl = (const float*)d_in[4];
  const float* il = (const float*)d_in[5];
  const float* plr = (const float*)d_in[6];
  float* out = (float*)d_out;
  float* ws = (float*)d_ws;

  prep_kernel<<<1, 256, 0, stream>>>(means, cov, tl, il, plr, ws);
  xq_kernel<<<(Bb * Nn) / 4, 256, 0, stream>>>(features, ws);
  emis_mfma_kernel<<<Bb * (Nn / 32), 256, 0, stream>>>(features, ws);
  scan_kernel<<<Bb / 4, 512, 0, stream>>>(lengths, ws, out);
}

// Round 3
// 1796.285 us; speedup vs baseline: 1.1679x; 1.1679x over previous
//
#include <hip/hip_runtime.h>
#include <math.h>

#define Bb 16
#define Nn 2048
#define Dd 256
#define Cc 128
#define Kk 20
#define BIG_NEG -1.0e9f

// workspace layout (float offsets)
#define WS_EMIS   0
#define WS_MSC    (WS_EMIS + Bb*Nn*Cc)          // means * inv_var, bf16  [C][D]
#define WS_XQ     (WS_MSC + Cc*Dd)              // sum f^2*inv_var  [B*N]
#define WS_ECHAN  (WS_XQ + Bb*Nn)               // const - 0.5*mq   [C]
#define WS_T      (WS_ECHAN + Cc)               // exp(trans_lp)    [C][C]
#define WS_LEN    (WS_T + Cc*Cc)                // len_lp           [K][C]
#define WS_INIT   (WS_LEN + Kk*Cc)              // init_lp          [C]
#define WS_IVAR   (WS_INIT + Cc)                // 1/cov            [D]

typedef __attribute__((ext_vector_type(8))) short short8;
typedef __attribute__((ext_vector_type(4))) float float4v;
typedef __attribute__((ext_vector_type(2))) float float2v;

__device__ __forceinline__ unsigned short f32_to_bf16(float x) {
  unsigned int u = __builtin_bit_cast(unsigned int, x);
  u = (u + 0x7FFFu + ((u >> 16) & 1u)) >> 16;
  return (unsigned short)u;
}

#define DPP_STEP(x, op, ctrl, rmask)                                          \
  do {                                                                        \
    int _yi = __builtin_amdgcn_update_dpp(                                    \
        __builtin_bit_cast(int, x), __builtin_bit_cast(int, x), ctrl, rmask,  \
        0xF, true);                                                           \
    x = op(x, __builtin_bit_cast(float, _yi));                                \
  } while (0)

__device__ __forceinline__ float dpp_add(float a, float b) { return a + b; }

__device__ __forceinline__ float wave_max64(float x) {
  DPP_STEP(x, fmaxf, 0xB1, 0xF);
  DPP_STEP(x, fmaxf, 0x4E, 0xF);
  DPP_STEP(x, fmaxf, 0x141, 0xF);
  DPP_STEP(x, fmaxf, 0x140, 0xF);
  DPP_STEP(x, fmaxf, 0x142, 0xA);
  DPP_STEP(x, fmaxf, 0x143, 0xC);
  return __builtin_bit_cast(float,
      __builtin_amdgcn_readlane(__builtin_bit_cast(int, x), 63));
}

__device__ __forceinline__ float wave_sum64(float x) {
  DPP_STEP(x, dpp_add, 0xB1, 0xF);
  DPP_STEP(x, dpp_add, 0x4E, 0xF);
  DPP_STEP(x, dpp_add, 0x141, 0xF);
  DPP_STEP(x, dpp_add, 0x140, 0xF);
  DPP_STEP(x, dpp_add, 0x142, 0xA);
  DPP_STEP(x, dpp_add, 0x143, 0xC);
  return __builtin_bit_cast(float,
      __builtin_amdgcn_readlane(__builtin_bit_cast(int, x), 63));
}

// ---------------- small precompute (1 block, 256 threads) ----------------
__global__ void prep_kernel(const float* __restrict__ means,
                            const float* __restrict__ cov,
                            const float* __restrict__ tl,
                            const float* __restrict__ il,
                            const float* __restrict__ plr,
                            float* __restrict__ ws) {
  __shared__ float s_iv[Dd];
  __shared__ float s_red[4];
  __shared__ float s_tlse[Cc];
  int tid = threadIdx.x;

  float cv = cov[tid];
  float iv = 1.0f / cv;
  s_iv[tid] = iv;
  ws[WS_IVAR + tid] = iv;
  float lg = __logf(cv);
  #pragma unroll
  for (int off = 1; off < 64; off <<= 1) lg += __shfl_xor(lg, off, 64);
  if ((tid & 63) == 0) s_red[tid >> 6] = lg;
  __syncthreads();
  float logdet = s_red[0] + s_red[1] + s_red[2] + s_red[3];
  float cconst = -0.5f * ((float)Dd * 1.8378770664093453f + logdet);

  // msc in bf16 (B-frag operand for emission MFMA)
  unsigned short* mscb = (unsigned short*)(ws + WS_MSC);
  for (int idx = tid; idx < Cc * Dd; idx += 256) {
    int d = idx & (Dd - 1);
    mscb[idx] = f32_to_bf16(means[idx] * s_iv[d]);
  }
  if (tid < Cc) {
    float acc = 0.0f;
    for (int d = 0; d < Dd; d++) {
      float m = means[tid * Dd + d];
      acc = fmaf(m * m, s_iv[d], acc);
    }
    ws[WS_ECHAN + tid] = cconst - 0.5f * acc;
  }
  for (int idx = tid; idx < Kk * Cc; idx += 256) {
    int L = idx / Cc + 1;
    int c = idx & (Cc - 1);
    float r = plr[c];
    ws[WS_LEN + idx] = (float)L * r - __expf(r) - lgammaf((float)(L + 1));
  }

  __syncthreads();
  float x = (tid < Cc) ? il[tid] : -INFINITY;
  float mx = x;
  #pragma unroll
  for (int off = 1; off < 64; off <<= 1) mx = fmaxf(mx, __shfl_xor(mx, off, 64));
  if ((tid & 63) == 0) s_red[tid >> 6] = mx;
  __syncthreads();
  float M = fmaxf(s_red[0], s_red[1]);
  float se = (tid < Cc) ? __expf(x - M) : 0.0f;
  #pragma unroll
  for (int off = 1; off < 64; off <<= 1) se += __shfl_xor(se, off, 64);
  __syncthreads();
  if ((tid & 63) == 0) s_red[tid >> 6] = se;
  __syncthreads();
  float lse = M + __logf(s_red[0] + s_red[1]);
  if (tid < Cc) ws[WS_INIT + tid] = x - lse;

  if (tid < Cc) {
    int j = tid;
    float m2 = -INFINITY;
    for (int i = 0; i < Cc; i++) if (i != j) m2 = fmaxf(m2, tl[i * Cc + j]);
    float s2 = 0.0f;
    for (int i = 0; i < Cc; i++) if (i != j) s2 += __expf(tl[i * Cc + j] - m2);
    s_tlse[j] = m2 + __logf(s2);
  }
  __syncthreads();
  for (int idx = tid; idx < Cc * Cc; idx += 256) {
    int i = idx / Cc;
    int j = idx & (Cc - 1);
    ws[WS_T + idx] = (i == j) ? 0.0f : __expf(tl[idx] - s_tlse[j]);
  }
}

// ---------------- xq[b,n] = sum_d f^2 * inv_var (one wave per position) ----------------
__global__ void xq_kernel(const float* __restrict__ f, float* __restrict__ ws) {
  int pos = blockIdx.x * 4 + (threadIdx.x >> 6);
  int lane = threadIdx.x & 63;
  const float4 fv = *(const float4*)&f[(size_t)pos * Dd + lane * 4];
  const float4 vv = *(const float4*)&ws[WS_IVAR + lane * 4];
  float a = fv.x * fv.x * vv.x + fv.y * fv.y * vv.y +
            fv.z * fv.z * vv.z + fv.w * fv.w * vv.w;
  #pragma unroll
  for (int off = 1; off < 64; off <<= 1) a += __shfl_xor(a, off, 64);
  if (lane == 0) ws[WS_XQ + pos] = a;
}

// ---------------- emission via MFMA: 32n x 128c per block, 4 waves ----------------
__launch_bounds__(256)
__global__ void emis_mfma_kernel(const float* __restrict__ f, float* __restrict__ ws) {
  const unsigned short* msc = (const unsigned short*)(ws + WS_MSC);
  float* emis = ws + WS_EMIS;
  int tid = threadIdx.x;
  int w = tid >> 6, lane = tid & 63, g = lane >> 4, l16 = lane & 15;
  int b = blockIdx.x >> 6;
  int n0 = (blockIdx.x & 63) << 5;
  int c0 = w << 5;

  const float* fbase = f + (size_t)(b * Nn + n0) * Dd;
  float4v acc[2][2];
  #pragma unroll
  for (int rt = 0; rt < 2; rt++)
    #pragma unroll
    for (int ct = 0; ct < 2; ct++) acc[rt][ct] = (float4v){0.f, 0.f, 0.f, 0.f};

  #pragma unroll
  for (int k0 = 0; k0 < Dd; k0 += 32) {
    int kk = k0 + g * 8;
    short8 afr[2], bfr[2];
    #pragma unroll
    for (int rt = 0; rt < 2; rt++) {
      const float* src = fbase + (size_t)(rt * 16 + l16) * Dd + kk;
      float4 v0 = *(const float4*)src;
      float4 v1 = *(const float4*)(src + 4);
      short8 fr;
      fr[0] = (short)f32_to_bf16(v0.x); fr[1] = (short)f32_to_bf16(v0.y);
      fr[2] = (short)f32_to_bf16(v0.z); fr[3] = (short)f32_to_bf16(v0.w);
      fr[4] = (short)f32_to_bf16(v1.x); fr[5] = (short)f32_to_bf16(v1.y);
      fr[6] = (short)f32_to_bf16(v1.z); fr[7] = (short)f32_to_bf16(v1.w);
      afr[rt] = fr;
    }
    #pragma unroll
    for (int ct = 0; ct < 2; ct++)
      bfr[ct] = *(const short8*)&msc[(size_t)(c0 + ct * 16 + l16) * Dd + kk];
    #pragma unroll
    for (int rt = 0; rt < 2; rt++)
      #pragma unroll
      for (int ct = 0; ct < 2; ct++)
        acc[rt][ct] = __builtin_amdgcn_mfma_f32_16x16x32_bf16(afr[rt], bfr[ct], acc[rt][ct], 0, 0, 0);
  }

  #pragma unroll
  for (int rt = 0; rt < 2; rt++) {
    #pragma unroll
    for (int ct = 0; ct < 2; ct++) {
      int cc = c0 + ct * 16 + l16;
      float ec = ws[WS_ECHAN + cc];
      #pragma unroll
      for (int r = 0; r < 4; r++) {
        int row = rt * 16 + g * 4 + r;
        int nn = n0 + row;
        emis[(size_t)(b * Nn + nn) * Cc + cc] =
            ec - 0.5f * ws[WS_XQ + b * Nn + nn] + acc[rt][ct][r];
      }
    }
  }
}

// ---------------- semi-Markov scan: ONE WAVE per batch, zero barriers ----------------
// Lane l owns channels c0 = (l>>4)*32 + (l&15), c1 = c0 + 16 (so after the matvec the
// needed outputs land in-lane: tile 2g holds q[c0], tile 2g+1 holds q[c1] at col l&15).
// Multiplicative state (invariants verified in round 2): q = exp(beta_t - A_t);
// E[s] = exp(beta_{t-1-s} - cum_{t-1-s} + cum_t - A_t); A_t = A_{t-1} + me_t + log wv_t
// (deadbeat, fresh wave-max each step -> stable; stale scales have unit-circle poles).
// Per step (serial chain, NO transcendentals on it):
//   S = fma(q, elen0, Stail); v = S*ee; store bf16(v) (UNNORMALIZED - bf16 is scale-free);
//   ds_write_b16 x2 -> lgkmcnt -> ds_read_b128 x4 (broadcast) -> 8 tile-MFMAs (2+2 chains)
//   -> q = (x+y)*r  [r = rcp(wave_max(v)) computed in the LDS/MFMA shadow].
// Off-path: sch = ee*r; E-shift 19 pk-muls; Stail = 19 pk-fma tree; Kahan Dlt with
// dla = me + log wv; emission prefetch 8 rows/group; 2 expf (ee) per step.
__launch_bounds__(64, 1)
__global__ void scan_kernel(const int* __restrict__ lengths,
                            const float* __restrict__ ws,
                            float* __restrict__ out) {
  __shared__ __align__(16) unsigned short p_lds[Cc];  // 256 B, same-wave use only

  int lane = threadIdx.x;
  int g = lane >> 4;
  int l15 = lane & 15;
  int c0 = g * 32 + l15;
  int c1 = c0 + 16;
  int b = blockIdx.x;
  int len_b = lengths[b];
  const float* emis = ws + WS_EMIS + (size_t)b * Nn * Cc;

  // T fragments (MFMA B operand), 8 n-tiles x 4 k-chunks:
  // lane holds T[nt*16 + l15][kc*32 + g*8 + j]  (q_out[i] = sum_j p[j] * Texp[i][j])
  short8 Tf[8][4];
  {
    const float* T = ws + WS_T;
    #pragma unroll
    for (int nt = 0; nt < 8; nt++)
      #pragma unroll
      for (int kc = 0; kc < 4; kc++) {
        const float* src = &T[(size_t)(nt * 16 + l15) * Cc + kc * 32 + g * 8];
        short8 fr;
        #pragma unroll
        for (int j = 0; j < 8; j++) fr[j] = (short)f32_to_bf16(src[j]);
        Tf[nt][kc] = fr;
      }
  }

  // elen[k] = exp(length lp for duration k+1), per owned channel pair
  float2v elen[Kk];
  #pragma unroll
  for (int k = 0; k < Kk; k++)
    elen[k] = (float2v){__expf(ws[WS_LEN + k * Cc + c0]),
                        __expf(ws[WS_LEN + k * Cc + c1])};

  // E[s] = duration slot k = s+2 (k=1 carried by q)
  float2v E[Kk - 1];
  #pragma unroll
  for (int s = 0; s < Kk - 1; s++) E[s] = (float2v){0.0f, 0.0f};

  float2v q = (float2v){__expf(ws[WS_INIT + c0]), __expf(ws[WS_INIT + c1])};
  float2v Stail = (float2v){0.0f, 0.0f};
  float2v cum = (float2v){0.0f, 0.0f};
  float2v Dlt = (float2v){0.0f, 0.0f};
  float2v dcomp = (float2v){0.0f, 0.0f};

  // emission prefetch: e[i] = row (t-1) for step t = tg+i
  float2v e[8], en[8];
  float me[8];
  #pragma unroll
  for (int j = 0; j < 8; j++)
    e[j] = (float2v){emis[(size_t)j * Cc + c0], emis[(size_t)j * Cc + c1]};
  #pragma unroll
  for (int j = 0; j < 8; j++) me[j] = wave_max64(fmaxf(e[j].x, e[j].y));
  float2v ee = (float2v){__expf(e[0].x - me[0]), __expf(e[0].y - me[0])};

  bool done = false;
  for (int tg = 1; tg <= Nn && !done; tg += 8) {
    #pragma unroll
    for (int i = 0; i < 8; i++) {
      int t = tg + i;
      float2v ecur = e[i];
      float2v S = q * elen[0] + Stail;

      if (t == len_b) {
        float ax = cum.x + ecur.x + Dlt.x + __logf(fmaxf(S.x, 1e-37f));
        float ay = cum.y + ecur.y + Dlt.y + __logf(fmaxf(S.y, 1e-37f));
        float Mb = wave_max64(fmaxf(ax, ay));
        float ps = wave_sum64(__expf(ax - Mb) + __expf(ay - Mb));
        if (lane == 0) out[b] = Mb + __logf(ps);
        done = true;
        break;
      }

      float2v v = S * ee;                 // exp(alpha_t - A_{t-1} - me_t), unnormalized
      p_lds[c0] = f32_to_bf16(v.x);
      p_lds[c1] = f32_to_bf16(v.y);
      asm volatile("s_waitcnt lgkmcnt(0)" ::: "memory");  // same-wave RAW through LDS
      short8 pa0 = *(const short8*)&p_lds[g * 8];
      short8 pa1 = *(const short8*)&p_lds[32 + g * 8];
      short8 pa2 = *(const short8*)&p_lds[64 + g * 8];
      short8 pa3 = *(const short8*)&p_lds[96 + g * 8];

      // scale (in the LDS/MFMA latency shadow)
      float wv = fmaxf(wave_max64(fmaxf(v.x, v.y)), 1.0e-30f);
      float r = __builtin_amdgcn_rcpf(wv);

      if (i == 0) {   // group prefetch: rows tg+7 .. tg+14
        #pragma unroll
        for (int j = 0; j < 8; j++) {
          int rr = tg + 7 + j;
          if (rr > Nn - 1) rr = Nn - 1;
          en[j] = (float2v){emis[(size_t)rr * Cc + c0], emis[(size_t)rr * Cc + c1]};
        }
      }

      // matvec: 8 tiles, 2+2 k-chunks (only acc[0] used: rows replicated)
      float4v z = {0.0f, 0.0f, 0.0f, 0.0f};
      float qv[8];
      #pragma unroll
      for (int nt = 0; nt < 8; nt++) {
        float4v x = __builtin_amdgcn_mfma_f32_16x16x32_bf16(pa1, Tf[nt][1],
                      __builtin_amdgcn_mfma_f32_16x16x32_bf16(pa0, Tf[nt][0], z, 0, 0, 0),
                      0, 0, 0);
        float4v y = __builtin_amdgcn_mfma_f32_16x16x32_bf16(pa3, Tf[nt][3],
                      __builtin_amdgcn_mfma_f32_16x16x32_bf16(pa2, Tf[nt][2], z, 0, 0, 0),
                      0, 0, 0);
        qv[nt] = x[0] + y[0];
      }

      // off-path state update (uses OLD q before reassignment)
      float2v sch = ee * r;               // exp(e_t - dla)
      #pragma unroll
      for (int s = Kk - 2; s >= 1; s--) E[s] = E[s - 1] * sch;
      E[0] = q * sch;

      float2v s0 = E[0] * elen[1];
      float2v s1 = E[1] * elen[2];
      float2v s2 = E[2] * elen[3];
      float2v s3 = E[3] * elen[4];
      s0 = E[4] * elen[5] + s0;   s1 = E[5] * elen[6] + s1;
      s2 = E[6] * elen[7] + s2;   s3 = E[7] * elen[8] + s3;
      s0 = E[8] * elen[9] + s0;   s1 = E[9] * elen[10] + s1;
      s2 = E[10] * elen[11] + s2; s3 = E[11] * elen[12] + s3;
      s0 = E[12] * elen[13] + s0; s1 = E[13] * elen[14] + s1;
      s2 = E[14] * elen[15] + s2; s3 = E[15] * elen[16] + s3;
      s0 = E[16] * elen[17] + s0; s1 = E[17] * elen[18] + s1;
      s2 = E[18] * elen[19] + s2;
      Stail = (s0 + s1) + (s2 + s3);

      // accounting: dla = me + log wv (off the serial chain)
      float dla = me[i] + __logf(wv);
      float2v dd = (float2v){dla, dla} - ecur;
      float2v yk = dd - dcomp;
      float2v t2 = Dlt + yk;
      dcomp = (t2 - Dlt) - yk;
      Dlt = t2;
      cum += ecur;

      if (i >= 2) me[i - 2] = wave_max64(fmaxf(en[i - 2].x, en[i - 2].y));
      if (i < 7)
        ee = (float2v){__expf(e[i + 1].x - me[i + 1]),
                       __expf(e[i + 1].y - me[i + 1])};

      // in-lane select: q[c0] = tile 2g, q[c1] = tile 2g+1 (col l15)
      float q0 = (g & 2) ? ((g & 1) ? qv[6] : qv[4]) : ((g & 1) ? qv[2] : qv[0]);
      float q1 = (g & 2) ? ((g & 1) ? qv[7] : qv[5]) : ((g & 1) ? qv[3] : qv[1]);
      q = (float2v){q0 * r, q1 * r};      // exp(beta_t - A_t), exactly
    }
    if (!done) {
      me[6] = wave_max64(fmaxf(en[6].x, en[6].y));
      me[7] = wave_max64(fmaxf(en[7].x, en[7].y));
      #pragma unroll
      for (int j = 0; j < 8; j++) e[j] = en[j];
      ee = (float2v){__expf(e[0].x - me[0]), __expf(e[0].y - me[0])};
    }
  }
}

extern "C" void kernel_launch(void* const* d_in, const int* in_sizes, int n_in,
                              void* d_out, int out_size, void* d_ws, size_t ws_size,
                              hipStream_t stream) {
  const float* features = (const float*)d_in[0];
  const int* lengths = (const int*)d_in[1];
  const float* means = (const float*)d_in[2];
  const float* cov = (const float*)d_in[3];
  const float* tl = (const float*)d_in[4];
  const float* il = (const float*)d_in[5];
  const float* plr = (const float*)d_in[6];
  float* out = (float*)d_out;
  float* ws = (float*)d_ws;

  prep_kernel<<<1, 256, 0, stream>>>(means, cov, tl, il, plr, ws);
  xq_kernel<<<(Bb * Nn) / 4, 256, 0, stream>>>(features, ws);
  emis_mfma_kernel<<<Bb * (Nn / 32), 256, 0, stream>>>(features, ws);
  scan_kernel<<<Bb, 64, 0, stream>>>(lengths, ws, out);
}

// Round 4
// 1559.461 us; speedup vs baseline: 1.3453x; 1.1519x over previous
//
#include <hip/hip_runtime.h>
#include <math.h>

#define Bb 16
#define Nn 2048
#define Dd 256
#define Cc 128
#define Kk 20
#define BIG_NEG -1.0e9f

// workspace layout (float offsets)
#define WS_EMIS   0
#define WS_MSC    (WS_EMIS + Bb*Nn*Cc)          // means * inv_var, bf16  [C][D]
#define WS_XQ     (WS_MSC + Cc*Dd)              // sum f^2*inv_var  [B*N]
#define WS_ECHAN  (WS_XQ + Bb*Nn)               // const - 0.5*mq   [C]
#define WS_T      (WS_ECHAN + Cc)               // exp(trans_lp)    [C][C]
#define WS_LEN    (WS_T + Cc*Cc)                // len_lp           [K][C]
#define WS_INIT   (WS_LEN + Kk*Cc)              // init_lp          [C]
#define WS_IVAR   (WS_INIT + Cc)                // 1/cov            [D]

typedef __attribute__((ext_vector_type(8))) short short8;
typedef __attribute__((ext_vector_type(4))) float float4v;

__device__ __forceinline__ unsigned short f32_to_bf16(float x) {
  unsigned int u = __builtin_bit_cast(unsigned int, x);
  u = (u + 0x7FFFu + ((u >> 16) & 1u)) >> 16;
  return (unsigned short)u;
}

#define DPP_STEP(x, op, ctrl, rmask)                                          \
  do {                                                                        \
    int _yi = __builtin_amdgcn_update_dpp(                                    \
        __builtin_bit_cast(int, x), __builtin_bit_cast(int, x), ctrl, rmask,  \
        0xF, true);                                                           \
    x = op(x, __builtin_bit_cast(float, _yi));                                \
  } while (0)

__device__ __forceinline__ float dpp_add(float a, float b) { return a + b; }

__device__ __forceinline__ float wave_max64(float x) {
  DPP_STEP(x, fmaxf, 0xB1, 0xF);
  DPP_STEP(x, fmaxf, 0x4E, 0xF);
  DPP_STEP(x, fmaxf, 0x141, 0xF);
  DPP_STEP(x, fmaxf, 0x140, 0xF);
  DPP_STEP(x, fmaxf, 0x142, 0xA);
  DPP_STEP(x, fmaxf, 0x143, 0xC);
  return __builtin_bit_cast(float,
      __builtin_amdgcn_readlane(__builtin_bit_cast(int, x), 63));
}

__device__ __forceinline__ float wave_sum64(float x) {
  DPP_STEP(x, dpp_add, 0xB1, 0xF);
  DPP_STEP(x, dpp_add, 0x4E, 0xF);
  DPP_STEP(x, dpp_add, 0x141, 0xF);
  DPP_STEP(x, dpp_add, 0x140, 0xF);
  DPP_STEP(x, dpp_add, 0x142, 0xA);
  DPP_STEP(x, dpp_add, 0x143, 0xC);
  return __builtin_bit_cast(float,
      __builtin_amdgcn_readlane(__builtin_bit_cast(int, x), 63));
}

// ---------------- small precompute (1 block, 256 threads) ----------------
__global__ void prep_kernel(const float* __restrict__ means,
                            const float* __restrict__ cov,
                            const float* __restrict__ tl,
                            const float* __restrict__ il,
                            const float* __restrict__ plr,
                            float* __restrict__ ws) {
  __shared__ float s_iv[Dd];
  __shared__ float s_red[4];
  __shared__ float s_tlse[Cc];
  int tid = threadIdx.x;

  float cv = cov[tid];
  float iv = 1.0f / cv;
  s_iv[tid] = iv;
  ws[WS_IVAR + tid] = iv;
  float lg = __logf(cv);
  #pragma unroll
  for (int off = 1; off < 64; off <<= 1) lg += __shfl_xor(lg, off, 64);
  if ((tid & 63) == 0) s_red[tid >> 6] = lg;
  __syncthreads();
  float logdet = s_red[0] + s_red[1] + s_red[2] + s_red[3];
  float cconst = -0.5f * ((float)Dd * 1.8378770664093453f + logdet);

  // msc in bf16 (B-frag operand for emission MFMA)
  unsigned short* mscb = (unsigned short*)(ws + WS_MSC);
  for (int idx = tid; idx < Cc * Dd; idx += 256) {
    int d = idx & (Dd - 1);
    mscb[idx] = f32_to_bf16(means[idx] * s_iv[d]);
  }
  if (tid < Cc) {
    float acc = 0.0f;
    for (int d = 0; d < Dd; d++) {
      float m = means[tid * Dd + d];
      acc = fmaf(m * m, s_iv[d], acc);
    }
    ws[WS_ECHAN + tid] = cconst - 0.5f * acc;
  }
  for (int idx = tid; idx < Kk * Cc; idx += 256) {
    int L = idx / Cc + 1;
    int c = idx & (Cc - 1);
    float r = plr[c];
    ws[WS_LEN + idx] = (float)L * r - __expf(r) - lgammaf((float)(L + 1));
  }

  __syncthreads();
  float x = (tid < Cc) ? il[tid] : -INFINITY;
  float mx = x;
  #pragma unroll
  for (int off = 1; off < 64; off <<= 1) mx = fmaxf(mx, __shfl_xor(mx, off, 64));
  if ((tid & 63) == 0) s_red[tid >> 6] = mx;
  __syncthreads();
  float M = fmaxf(s_red[0], s_red[1]);
  float se = (tid < Cc) ? __expf(x - M) : 0.0f;
  #pragma unroll
  for (int off = 1; off < 64; off <<= 1) se += __shfl_xor(se, off, 64);
  __syncthreads();
  if ((tid & 63) == 0) s_red[tid >> 6] = se;
  __syncthreads();
  float lse = M + __logf(s_red[0] + s_red[1]);
  if (tid < Cc) ws[WS_INIT + tid] = x - lse;

  if (tid < Cc) {
    int j = tid;
    float m2 = -INFINITY;
    for (int i = 0; i < Cc; i++) if (i != j) m2 = fmaxf(m2, tl[i * Cc + j]);
    float s2 = 0.0f;
    for (int i = 0; i < Cc; i++) if (i != j) s2 += __expf(tl[i * Cc + j] - m2);
    s_tlse[j] = m2 + __logf(s2);
  }
  __syncthreads();
  for (int idx = tid; idx < Cc * Cc; idx += 256) {
    int i = idx / Cc;
    int j = idx & (Cc - 1);
    ws[WS_T + idx] = (i == j) ? 0.0f : __expf(tl[idx] - s_tlse[j]);
  }
}

// ---------------- xq[b,n] = sum_d f^2 * inv_var (one wave per position) ----------------
__global__ void xq_kernel(const float* __restrict__ f, float* __restrict__ ws) {
  int pos = blockIdx.x * 4 + (threadIdx.x >> 6);
  int lane = threadIdx.x & 63;
  const float4 fv = *(const float4*)&f[(size_t)pos * Dd + lane * 4];
  const float4 vv = *(const float4*)&ws[WS_IVAR + lane * 4];
  float a = fv.x * fv.x * vv.x + fv.y * fv.y * vv.y +
            fv.z * fv.z * vv.z + fv.w * fv.w * vv.w;
  #pragma unroll
  for (int off = 1; off < 64; off <<= 1) a += __shfl_xor(a, off, 64);
  if (lane == 0) ws[WS_XQ + pos] = a;
}

// ---------------- emission via MFMA: 32n x 128c per block, 4 waves ----------------
__launch_bounds__(256)
__global__ void emis_mfma_kernel(const float* __restrict__ f, float* __restrict__ ws) {
  const unsigned short* msc = (const unsigned short*)(ws + WS_MSC);
  float* emis = ws + WS_EMIS;
  int tid = threadIdx.x;
  int w = tid >> 6, lane = tid & 63, g = lane >> 4, l16 = lane & 15;
  int b = blockIdx.x >> 6;
  int n0 = (blockIdx.x & 63) << 5;
  int c0 = w << 5;

  const float* fbase = f + (size_t)(b * Nn + n0) * Dd;
  float4v acc[2][2];
  #pragma unroll
  for (int rt = 0; rt < 2; rt++)
    #pragma unroll
    for (int ct = 0; ct < 2; ct++) acc[rt][ct] = (float4v){0.f, 0.f, 0.f, 0.f};

  #pragma unroll
  for (int k0 = 0; k0 < Dd; k0 += 32) {
    int kk = k0 + g * 8;
    short8 afr[2], bfr[2];
    #pragma unroll
    for (int rt = 0; rt < 2; rt++) {
      const float* src = fbase + (size_t)(rt * 16 + l16) * Dd + kk;
      float4 v0 = *(const float4*)src;
      float4 v1 = *(const float4*)(src + 4);
      short8 fr;
      fr[0] = (short)f32_to_bf16(v0.x); fr[1] = (short)f32_to_bf16(v0.y);
      fr[2] = (short)f32_to_bf16(v0.z); fr[3] = (short)f32_to_bf16(v0.w);
      fr[4] = (short)f32_to_bf16(v1.x); fr[5] = (short)f32_to_bf16(v1.y);
      fr[6] = (short)f32_to_bf16(v1.z); fr[7] = (short)f32_to_bf16(v1.w);
      afr[rt] = fr;
    }
    #pragma unroll
    for (int ct = 0; ct < 2; ct++)
      bfr[ct] = *(const short8*)&msc[(size_t)(c0 + ct * 16 + l16) * Dd + kk];
    #pragma unroll
    for (int rt = 0; rt < 2; rt++)
      #pragma unroll
      for (int ct = 0; ct < 2; ct++)
        acc[rt][ct] = __builtin_amdgcn_mfma_f32_16x16x32_bf16(afr[rt], bfr[ct], acc[rt][ct], 0, 0, 0);
  }

  #pragma unroll
  for (int rt = 0; rt < 2; rt++) {
    #pragma unroll
    for (int ct = 0; ct < 2; ct++) {
      int cc = c0 + ct * 16 + l16;
      float ec = ws[WS_ECHAN + cc];
      #pragma unroll
      for (int r = 0; r < 4; r++) {
        int row = rt * 16 + g * 4 + r;
        int nn = n0 + row;
        emis[(size_t)(b * Nn + nn) * Cc + cc] =
            ec - 0.5f * ws[WS_XQ + b * Nn + nn] + acc[rt][ct][r];
      }
    }
  }
}

// ---------------- semi-Markov scan: 2 waves per batch, 1 barrier/step ----------------
// Wave w owns channels c = w*64 + lane (one per lane) and output tiles w*4+0..3
// (Tf = 64 VGPR/wave; total live ~160 -> no spill, unlike the 1-wave 270-VGPR version).
// Multiplicative state (invariants verified rounds 2-3): q = exp(beta_t - A_t);
// E[s] = exp(beta_{t-1-s} - cum_{t-1-s} + cum_t - A_t); A_t = A_{t-1} + me_t + log wv_t
// (fresh cross-wave max each step = deadbeat/stable; stale scales diverge).
// p stored in LDS UNNORMALIZED bf16 (scale-free); single shared scale r = rcp(wv)
// applied post-matvec by both waves identically -> no two-scale combine on the chain.
// me (cross-wave emission row max) exchanged via group-parity double-buffered LDS,
// every slot written >=1 barrier before any read (schedule: slot j<=5 written at i=j+2,
// slots 6,7 at i=6,7; read earliest next group at i=j-1).
__launch_bounds__(128, 1)
__global__ void scan_kernel(const int* __restrict__ lengths,
                            const float* __restrict__ ws,
                            float* __restrict__ out) {
  __shared__ __align__(16) unsigned short p_lds[2][Cc];  // ping-pong, unnormalized bf16
  __shared__ float lds_wv[2][2];        // [buf][wave] per-wave max of v
  __shared__ float lds_men[2][2][8];    // [group parity][wave][slot] emission row max
  __shared__ float lds_out[2][2];       // [{M, ps}][wave]

  int tid = threadIdx.x;
  int w = tid >> 6;
  int lane = tid & 63;
  int g = lane >> 4;
  int l15 = lane & 15;
  int c = w * 64 + lane;
  int b = blockIdx.x;
  int len_b = lengths[b];
  const float* emis = ws + WS_EMIS + (size_t)b * Nn * Cc;

  // T fragments (MFMA B operand), this wave's 4 tiles x 4 k-chunks:
  // lane holds T[(w*4+nt)*16 + l15][kc*32 + g*8 + j]
  short8 Tf[4][4];
  {
    const float* T = ws + WS_T;
    #pragma unroll
    for (int nt = 0; nt < 4; nt++)
      #pragma unroll
      for (int kc = 0; kc < 4; kc++) {
        const float* src = &T[(size_t)((w * 4 + nt) * 16 + l15) * Cc + kc * 32 + g * 8];
        short8 fr;
        #pragma unroll
        for (int j = 0; j < 8; j++) fr[j] = (short)f32_to_bf16(src[j]);
        Tf[nt][kc] = fr;
      }
  }

  // elen[k] = exp(length lp for duration k+1) for owned channel
  float elen[Kk];
  #pragma unroll
  for (int k = 0; k < Kk; k++) elen[k] = __expf(ws[WS_LEN + k * Cc + c]);
  float elen0 = elen[0];

  // E[s] = duration slot k = s+2 (k=1 carried by q)
  float E[Kk - 1];
  #pragma unroll
  for (int s = 0; s < Kk - 1; s++) E[s] = 0.0f;

  float q = __expf(ws[WS_INIT + c]);   // exp(beta_0 - A_0), A_0 = 0
  float Stail = 0.0f;
  float cum = 0.0f;                    // exact-order cumsum (matches reference)
  float Dlt = 0.0f, dcomp = 0.0f;      // Kahan Delta = A_{t-1} - cum[t-1]

  // emission prefetch: e[i] = row (t-1) for step t = tg+i
  float e[8], en[8];
  #pragma unroll
  for (int j = 0; j < 8; j++) e[j] = emis[(size_t)j * Cc + c];
  #pragma unroll
  for (int j = 0; j < 8; j++) {
    float m = wave_max64(e[j]);
    if (lane == 0) lds_men[0][w][j] = m;
  }
  __syncthreads();
  float ee = __expf(e[0] - fmaxf(lds_men[0][0][0], lds_men[0][1][0]));

  bool done = false;
  for (int tg = 1; tg <= Nn && !done; tg += 8) {
    int gp = ((tg - 1) >> 3) & 1;      // current group's me buffer parity
    #pragma unroll
    for (int i = 0; i < 8; i++) {
      int t = tg + i;
      int buf = t & 1;
      bool fin = (t == len_b);
      float ecur = e[i];
      float S = fmaf(q, elen0, Stail);
      float a = 0.0f;

      // ---- pre-barrier ----
      if (fin) {
        a = (cum + ecur) + Dlt + __logf(fmaxf(S, 1e-37f));
        float Mw = wave_max64(a);
        if (lane == 0) lds_out[0][w] = Mw;
      } else {
        float v = S * ee;                        // exp(alpha_t - A_{t-1} - me_t)
        p_lds[buf][c] = f32_to_bf16(v);          // unnormalized (bf16 = scale-free)
        float wvp = wave_max64(v);               // runs parallel to cvt+ds_write
        if (lane == 0) lds_wv[buf][w] = wvp;
      }
      __syncthreads();                           // the ONE barrier per step

      // ---- post-barrier ----
      if (fin) {
        float Mb = fmaxf(lds_out[0][0], lds_out[0][1]);
        float ps = wave_sum64(__expf(a - Mb));
        if (lane == 0) lds_out[1][w] = ps;
        __syncthreads();
        if (tid == 0) out[b] = Mb + __logf(lds_out[1][0] + lds_out[1][1]);
        done = true;
        break;
      }

      // issue p-fragment LDS reads + shared scale early
      short8 pa0 = *(const short8*)&p_lds[buf][g * 8];
      short8 pa1 = *(const short8*)&p_lds[buf][32 + g * 8];
      short8 pa2 = *(const short8*)&p_lds[buf][64 + g * 8];
      short8 pa3 = *(const short8*)&p_lds[buf][96 + g * 8];
      float wv = fmaxf(fmaxf(lds_wv[buf][0], lds_wv[buf][1]), 1.0e-30f);
      float r = __builtin_amdgcn_rcpf(wv);

      if (i == 0) {   // group prefetch: rows tg+7 .. tg+14
        #pragma unroll
        for (int j = 0; j < 8; j++) {
          int rr = tg + 7 + j;
          if (rr > Nn - 1) rr = Nn - 1;
          en[j] = emis[(size_t)rr * Cc + c];
        }
      }

      // matvec: this wave's 4 tiles, 2+2 k-chunk chains
      float4v z = {0.0f, 0.0f, 0.0f, 0.0f};
      float qv[4];
      #pragma unroll
      for (int nt = 0; nt < 4; nt++) {
        float4v x = __builtin_amdgcn_mfma_f32_16x16x32_bf16(pa1, Tf[nt][1],
                      __builtin_amdgcn_mfma_f32_16x16x32_bf16(pa0, Tf[nt][0], z, 0, 0, 0),
                      0, 0, 0);
        float4v y = __builtin_amdgcn_mfma_f32_16x16x32_bf16(pa3, Tf[nt][3],
                      __builtin_amdgcn_mfma_f32_16x16x32_bf16(pa2, Tf[nt][2], z, 0, 0, 0),
                      0, 0, 0);
        qv[nt] = x[0] + y[0];
      }

      // off-path state update (uses OLD q)
      float sch = ee * r;               // exp(e_t - dla), dla = me + log wv
      #pragma unroll
      for (int s = Kk - 2; s >= 1; s--) E[s] = E[s - 1] * sch;
      E[0] = q * sch;

      float s0 = E[0] * elen[1];
      float s1 = E[1] * elen[2];
      float s2 = E[2] * elen[3];
      float s3 = E[3] * elen[4];
      s0 = fmaf(E[4], elen[5], s0);   s1 = fmaf(E[5], elen[6], s1);
      s2 = fmaf(E[6], elen[7], s2);   s3 = fmaf(E[7], elen[8], s3);
      s0 = fmaf(E[8], elen[9], s0);   s1 = fmaf(E[9], elen[10], s1);
      s2 = fmaf(E[10], elen[11], s2); s3 = fmaf(E[11], elen[12], s3);
      s0 = fmaf(E[12], elen[13], s0); s1 = fmaf(E[13], elen[14], s1);
      s2 = fmaf(E[14], elen[15], s2); s3 = fmaf(E[15], elen[16], s3);
      s0 = fmaf(E[16], elen[17], s0); s1 = fmaf(E[17], elen[18], s1);
      s2 = fmaf(E[18], elen[19], s2);
      Stail = (s0 + s1) + (s2 + s3);

      // accounting (off the serial chain): dla = me_comb[i] + log wv
      float meC = fmaxf(lds_men[gp][0][i], lds_men[gp][1][i]);
      float dla = meC + __logf(wv);
      {
        float dd = dla - ecur;
        float yk = dd - dcomp;
        float t2 = Dlt + yk;
        dcomp = (t2 - Dlt) - yk;
        Dlt = t2;
      }
      cum += ecur;

      // next-group me production (own-wave max -> LDS buf gp^1)
      if (i >= 2) {
        float m = wave_max64(en[i - 2]);
        if (lane == 0) lds_men[gp ^ 1][w][i - 2] = m;
      }
      if (i == 6) {
        float m = wave_max64(en[6]);
        if (lane == 0) lds_men[gp ^ 1][w][6] = m;
      }
      if (i == 7) {
        float m = wave_max64(en[7]);
        if (lane == 0) lds_men[gp ^ 1][w][7] = m;
      }

      // ee for next step (reads me_comb[i+1], written last group -> barrier-safe)
      if (i < 7) {
        float meN = fmaxf(lds_men[gp][0][i + 1], lds_men[gp][1][i + 1]);
        ee = __expf(e[i + 1] - meN);
      }

      // in-lane select: lane's channel c = w*64 + g*16 + l15 -> tile g, col l15
      float qs01 = (g & 1) ? qv[1] : qv[0];
      float qs23 = (g & 1) ? qv[3] : qv[2];
      float qs = (g & 2) ? qs23 : qs01;
      q = qs * r;                       // exp(beta_t - A_t), exactly
    }
    if (!done) {
      #pragma unroll
      for (int j = 0; j < 8; j++) e[j] = en[j];
      int gp = ((tg - 1) >> 3) & 1;
      float me0 = fmaxf(lds_men[gp ^ 1][0][0], lds_men[gp ^ 1][1][0]);
      ee = __expf(e[0] - me0);
    }
  }
}

extern "C" void kernel_launch(void* const* d_in, const int* in_sizes, int n_in,
                              void* d_out, int out_size, void* d_ws, size_t ws_size,
                              hipStream_t stream) {
  const float* features = (const float*)d_in[0];
  const int* lengths = (const int*)d_in[1];
  const float* means = (const float*)d_in[2];
  const float* cov = (const float*)d_in[3];
  const float* tl = (const float*)d_in[4];
  const float* il = (const float*)d_in[5];
  const float* plr = (const float*)d_in[6];
  float* out = (float*)d_out;
  float* ws = (float*)d_ws;

  prep_kernel<<<1, 256, 0, stream>>>(means, cov, tl, il, plr, ws);
  xq_kernel<<<(Bb * Nn) / 4, 256, 0, stream>>>(features, ws);
  emis_mfma_kernel<<<Bb * (Nn / 32), 256, 0, stream>>>(features, ws);
  scan_kernel<<<Bb, 128, 0, stream>>>(lengths, ws, out);
}